// Round 1
// baseline (42823.239 us; speedup 1.0000x reference)
//
#include <hip/hip_runtime.h>
#include <math.h>

// ---- problem constants ----
#define B_   32
#define L_   600
#define TW_  50
#define D_   768
#define MLP_ 3072
#define DEP_ 12
#define DD_  512
#define DDEP_ 4
#define C_   12
#define S_   612      // L + C
#define LK_  120      // len_keep
#define SE_  132      // encoder seq = C + len_keep
#define HE_  12       // encoder heads (hd=64)
#define HDE_ 64
#define HDN_ 16       // decoder heads (hd=32)
#define HDD_ 32
#define NPL_ 50       // L / C

__device__ __forceinline__ float wave_sum(float v){
  #pragma unroll
  for (int o = 32; o > 0; o >>= 1) v += __shfl_xor(v, o, 64);
  return v;
}
__device__ __forceinline__ float wave_max(float v){
  #pragma unroll
  for (int o = 32; o > 0; o >>= 1) v = fmaxf(v, __shfl_xor(v, o, 64));
  return v;
}

// per-token signal normalization: target = (sig - mu)/sqrt(var_ddof1 + 1e-6)
__global__ void k_signal_norm(const float* __restrict__ sig, float* __restrict__ tgt){
  int row = blockIdx.x; int lane = threadIdx.x;
  const float* p = sig + (size_t)row * TW_;
  float v = (lane < TW_) ? p[lane] : 0.f;
  float mean = wave_sum(v) * (1.f / TW_);
  float d = (lane < TW_) ? (v - mean) : 0.f;
  float var = wave_sum(d * d) * (1.f / (TW_ - 1));
  float rstd = rsqrtf(var + 1e-6f);
  if (lane < TW_) tgt[(size_t)row * TW_ + lane] = d * rstd;
}

// rank-based argsort of noise[0] (L=600, O(L^2), one block)
__global__ void k_argsort(const float* __restrict__ noise, float* __restrict__ m,
                          int* __restrict__ ids_restore, int* __restrict__ ids_keep){
  __shared__ float ns[L_];
  int t = threadIdx.x;
  if (t < L_) ns[t] = noise[t];
  __syncthreads();
  if (t < L_){
    float v = ns[t]; int r = 0;
    for (int j = 0; j < L_; ++j){
      float u = ns[j];
      r += (u < v) || (u == v && j < t);   // stable ascending
    }
    ids_restore[t] = r;
    m[t] = (r >= LK_) ? 1.f : 0.f;
    if (r < LK_) ids_keep[r] = t;
  }
}

// decoder attention "blocked" mask (S x S, uint8, 1 = blocked)
__global__ void k_build_mask(const float* __restrict__ m, unsigned char* __restrict__ blocked){
  int idx = blockIdx.x * 256 + threadIdx.x;
  if (idx >= S_ * S_) return;
  int i = idx / S_, j = idx % S_;
  bool allow;
  if (i < C_){
    if (j < C_) allow = (i == j);
    else        allow = (i == (j - C_) / NPL_);
  } else {
    int ii = i - C_;
    if (j < C_) allow = (ii / NPL_ == j);
    else {
      int jj = j - C_;
      if (m[ii] > 0.f) allow = ((ii % NPL_) == (jj % NPL_));
      else             allow = (m[jj] == 0.f);
    }
  }
  blocked[idx] = allow ? 0 : 1;
}

// transpose conv_w (D,TW,3) -> Bconv (150, D) with kk = k*TW + i
__global__ void k_prep_convw(const float* __restrict__ w, float* __restrict__ Bc){
  int idx = blockIdx.x * 256 + threadIdx.x;
  if (idx >= 150 * D_) return;
  int n = idx % D_; int kk = idx / D_;
  int i = kk % TW_; int k = kk / TW_;
  Bc[idx] = w[(size_t)n * 150 + i * 3 + k];
}

// im2col with wrap padding: P[(b,l), k*TW+i] = x0[b, (l+k-1) mod L, i]
__global__ void k_patch(const float* __restrict__ x0, float* __restrict__ P){
  int idx = blockIdx.x * 256 + threadIdx.x;
  if (idx >= B_ * L_ * 150) return;
  int kk = idx % 150; int mrow = idx / 150;
  int b = mrow / L_, l = mrow % L_;
  int i = kk % TW_, k = kk / TW_;
  int lw = l + k - 1; if (lw < 0) lw += L_; if (lw >= L_) lw -= L_;
  P[idx] = x0[((size_t)b * L_ + lw) * TW_ + i];
}

// x += spa_table[chan] + tem_table[time] + pos_embed[C+l]
__global__ void k_embed_add(float* __restrict__ x, const int* __restrict__ chan,
                            const int* __restrict__ timei, const float* __restrict__ spa,
                            const float* __restrict__ tem, const float* __restrict__ pos){
  int idx = blockIdx.x * 256 + threadIdx.x;
  if (idx >= B_ * L_ * D_) return;
  int d = idx % D_; int rl = idx / D_;
  int l = rl % L_;
  x[idx] += spa[(size_t)chan[rl] * D_ + d] + tem[(size_t)timei[rl] * D_ + d]
          + pos[(size_t)(C_ + l) * D_ + d];
}

// xe = [cls_token + pos_embed[:C] ; x[:, ids_keep, :]]
__global__ void k_gather_xe(const float* __restrict__ x, const float* __restrict__ cls,
                            const float* __restrict__ pos, const int* __restrict__ ids_keep,
                            float* __restrict__ xe){
  int idx = blockIdx.x * 256 + threadIdx.x;
  if (idx >= B_ * SE_ * D_) return;
  int d = idx % D_; int rs = idx / D_;
  int b = rs / SE_, s = rs % SE_;
  float v;
  if (s < C_) v = cls[(size_t)s * D_ + d] + pos[(size_t)s * D_ + d];
  else        v = x[((size_t)b * L_ + ids_keep[s - C_]) * D_ + d];
  xe[idx] = v;
}

// LayerNorm over last dim (dim = 768 or 512), eps 1e-5
__launch_bounds__(256)
__global__ void k_ln(const float* __restrict__ xin, const float* __restrict__ w,
                     const float* __restrict__ bb, float* __restrict__ outp, int dim){
  int row = blockIdx.x;
  const float* p = xin + (size_t)row * dim;
  float s = 0.f, sq = 0.f;
  for (int i = threadIdx.x; i < dim; i += 256){ float v = p[i]; s += v; sq += v * v; }
  __shared__ float rs[256], rq[256];
  rs[threadIdx.x] = s; rq[threadIdx.x] = sq;
  __syncthreads();
  for (int o = 128; o > 0; o >>= 1){
    if (threadIdx.x < o){ rs[threadIdx.x] += rs[threadIdx.x + o]; rq[threadIdx.x] += rq[threadIdx.x + o]; }
    __syncthreads();
  }
  float mean = rs[0] / dim;
  float var  = rq[0] / dim - mean * mean;
  float rstd = rsqrtf(var + 1e-5f);
  float* op = outp + (size_t)row * dim;
  for (int i = threadIdx.x; i < dim; i += 256) op[i] = (p[i] - mean) * rstd * w[i] + bb[i];
}

// Tiled fp32 GEMM: C[M,N] = A[M,K] @ B[K,N] (+bias)(gelu?)(+res).
// Requires M%64==0 and N%64==0 (holds for every call site); K arbitrary.
__launch_bounds__(256)
__global__ void gemm_f32(const float* __restrict__ A, const float* __restrict__ Bm,
                         float* __restrict__ Cm, const float* __restrict__ bias,
                         const float* __restrict__ res, int M, int N, int K, int gelu){
  __shared__ float As[16][68];
  __shared__ float Bs[16][68];
  int tid = threadIdx.x;
  int bm = blockIdx.y * 64, bn = blockIdx.x * 64;
  int tx = tid & 15, ty = tid >> 4;
  int ar = tid >> 2, ac = (tid & 3) * 4;   // A tile: row ar, 4 consecutive k from ac
  int bc = tid & 63, br = tid >> 6;        // B tile: col bc, rows br+4e
  const float* Ap = A + (size_t)(bm + ar) * K;
  float acc[4][4] = {};
  for (int k0 = 0; k0 < K; k0 += 16){
    #pragma unroll
    for (int e = 0; e < 4; ++e){
      int kk = ac + e;
      As[kk][ar] = (k0 + kk < K) ? Ap[k0 + kk] : 0.f;
    }
    #pragma unroll
    for (int e = 0; e < 4; ++e){
      int kr = br + e * 4;
      Bs[kr][bc] = (k0 + kr < K) ? Bm[(size_t)(k0 + kr) * N + bn + bc] : 0.f;
    }
    __syncthreads();
    #pragma unroll
    for (int k = 0; k < 16; ++k){
      float4 av = *reinterpret_cast<const float4*>(&As[k][ty * 4]);
      float4 bv = *reinterpret_cast<const float4*>(&Bs[k][tx * 4]);
      float a4[4] = {av.x, av.y, av.z, av.w};
      float b4[4] = {bv.x, bv.y, bv.z, bv.w};
      #pragma unroll
      for (int i = 0; i < 4; ++i)
        #pragma unroll
        for (int j = 0; j < 4; ++j)
          acc[i][j] += a4[i] * b4[j];
    }
    __syncthreads();
  }
  #pragma unroll
  for (int i = 0; i < 4; ++i){
    int row = bm + ty * 4 + i;
    #pragma unroll
    for (int j = 0; j < 4; ++j){
      int col = bn + tx * 4 + j;
      float v = acc[i][j];
      if (bias) v += bias[col];
      if (gelu){
        float x3 = v * v * v;
        v = 0.5f * v * (1.f + tanhf(0.7978845608028654f * (v + 0.044715f * x3)));
      }
      if (res) v += res[(size_t)row * N + col];
      Cm[(size_t)row * N + col] = v;
    }
  }
}

// encoder attention: 4 waves/block, one (b,h,q) per wave, hd=64, no mask
__launch_bounds__(256)
__global__ void k_attn_enc(const float* __restrict__ qkv, float* __restrict__ out){
  int bid = blockIdx.x;
  int qt = bid % (SE_ / 4); int bh = bid / (SE_ / 4);
  int h = bh % HE_; int b = bh / HE_;
  int wave = threadIdx.x >> 6, lane = threadIdx.x & 63;
  int q = qt * 4 + wave;
  __shared__ float qs[4][64];
  __shared__ float ps[4][SE_];
  const float* qr = qkv + ((size_t)(b * SE_ + q)) * (3 * D_) + h * HDE_;
  qs[wave][lane] = qr[lane];
  __syncthreads();
  float sc[3]; float mx = -1e30f;
  #pragma unroll
  for (int t = 0; t < 3; ++t){
    int k = lane + t * 64;
    if (k < SE_){
      const float* kr = qkv + ((size_t)(b * SE_ + k)) * (3 * D_) + D_ + h * HDE_;
      float dot = 0.f;
      for (int d = 0; d < HDE_; ++d) dot += qs[wave][d] * kr[d];
      sc[t] = dot * 0.125f;            // 1/sqrt(64)
      mx = fmaxf(mx, sc[t]);
    } else sc[t] = -1e30f;
  }
  mx = wave_max(mx);
  float sum = 0.f;
  #pragma unroll
  for (int t = 0; t < 3; ++t){
    int k = lane + t * 64;
    if (k < SE_){ float e = __expf(sc[t] - mx); ps[wave][k] = e; sum += e; }
  }
  sum = wave_sum(sum);
  __syncthreads();
  float inv = 1.f / sum;
  const float* vb = qkv + ((size_t)(b * SE_)) * (3 * D_) + 2 * D_ + h * HDE_ + lane;
  float o = 0.f;
  for (int k = 0; k < SE_; ++k) o += ps[wave][k] * vb[(size_t)k * (3 * D_)];
  out[((size_t)(b * SE_ + q)) * D_ + h * HDE_ + lane] = o * inv;
}

// decoder attention: 4 waves/block, one (b,h,q) per wave, hd=32, with blocked mask
__launch_bounds__(256)
__global__ void k_attn_dec(const float* __restrict__ qkv, const unsigned char* __restrict__ blocked,
                           float* __restrict__ out){
  int bid = blockIdx.x;
  int qt = bid % (S_ / 4); int bh = bid / (S_ / 4);
  int h = bh % HDN_; int b = bh / HDN_;
  int wave = threadIdx.x >> 6, lane = threadIdx.x & 63;
  int q = qt * 4 + wave;
  __shared__ float qs[4][32];
  __shared__ float ps[4][S_];
  const float* qr = qkv + ((size_t)(b * S_ + q)) * (3 * DD_) + h * HDD_;
  if (lane < 32) qs[wave][lane] = qr[lane];
  __syncthreads();
  const unsigned char* blk = blocked + (size_t)q * S_;
  float sc[10]; float mx = -1e30f;
  #pragma unroll
  for (int t = 0; t < 10; ++t){
    int k = lane + t * 64;
    if (k < S_){
      if (blk[k]) sc[t] = -1e9f;
      else {
        const float* kr = qkv + ((size_t)(b * S_ + k)) * (3 * DD_) + DD_ + h * HDD_;
        float dot = 0.f;
        for (int d = 0; d < HDD_; ++d) dot += qs[wave][d] * kr[d];
        sc[t] = dot * 0.17677669529663687f;   // 1/sqrt(32)
      }
      mx = fmaxf(mx, sc[t]);
    } else sc[t] = -1e30f;
  }
  mx = wave_max(mx);
  float sum = 0.f;
  #pragma unroll
  for (int t = 0; t < 10; ++t){
    int k = lane + t * 64;
    if (k < S_){ float e = __expf(sc[t] - mx); ps[wave][k] = e; sum += e; }
  }
  sum = wave_sum(sum);
  __syncthreads();
  float inv = 1.f / sum;
  int d = lane & 31, half = lane >> 5;
  const float* vb = qkv + ((size_t)(b * S_)) * (3 * DD_) + 2 * DD_ + h * HDD_ + d;
  float o = 0.f;
  for (int k = half * 306; k < half * 306 + 306; ++k) o += ps[wave][k] * vb[(size_t)k * (3 * DD_)];
  o += __shfl_xor(o, 32, 64);
  if (half == 0) out[((size_t)(b * S_ + q)) * DD_ + h * HDD_ + d] = o * inv;
}

// build decoder input: unshuffle + mask tokens + dec_pos_embed
__global__ void k_scatter_dec(const float* __restrict__ xdE, const int* __restrict__ ids_restore,
                              const float* __restrict__ mask_token, const float* __restrict__ dpos,
                              float* __restrict__ xd){
  int idx = blockIdx.x * 256 + threadIdx.x;
  if (idx >= B_ * S_ * DD_) return;
  int d = idx % DD_; int rs = idx / DD_;
  int b = rs / S_, s = rs % S_;
  float v;
  if (s < C_) v = xdE[((size_t)(b * SE_ + s)) * DD_ + d];
  else {
    int r = ids_restore[s - C_];
    v = (r < LK_) ? xdE[((size_t)(b * SE_ + C_ + r)) * DD_ + d] : mask_token[d];
  }
  xd[idx] = v + dpos[(size_t)s * DD_ + d];
}

// fused: pred = hd_row @ Wp + bp ; mse vs target ; masked atomic accumulate
__global__ void k_pred_loss(const float* __restrict__ hd, const float* __restrict__ Wp,
                            const float* __restrict__ bp, const float* __restrict__ tgt,
                            const float* __restrict__ m, float* __restrict__ loss){
  int r = blockIdx.x;          // b*L + i
  int i = r % L_;
  if (m[i] == 0.f) return;     // uniform per block
  int b = r / L_;
  __shared__ float hrow[DD_];
  const float* src = hd + ((size_t)(b * S_ + C_ + i)) * DD_;
  for (int j = threadIdx.x; j < DD_; j += 64) hrow[j] = src[j];
  __syncthreads();
  int n = threadIdx.x;
  float acc = 0.f;
  if (n < TW_){
    for (int k = 0; k < DD_; ++k) acc += hrow[k] * Wp[(size_t)k * TW_ + n];
    acc += bp[n];
    float e = acc - tgt[(size_t)r * TW_ + n];
    acc = e * e;
  }
  acc = wave_sum(acc);
  if (threadIdx.x == 0) atomicAdd(loss, acc * (1.f / TW_));
}

__global__ void k_zero(float* p){ if (threadIdx.x == 0) p[0] = 0.f; }
__global__ void k_finalize(const float* loss, float* out){
  if (threadIdx.x == 0) out[0] = loss[0] * (1.f / (float)(L_ - LK_));   // sum(m) = 480
}

extern "C" void kernel_launch(void* const* d_in, const int* in_sizes, int n_in,
                              void* d_out, int out_size, void* d_ws, size_t ws_size,
                              hipStream_t stream){
  (void)in_sizes; (void)n_in; (void)out_size; (void)ws_size;
  const float* signals = (const float*)d_in[0];
  const float* noise   = (const float*)d_in[1];
  const int*   chan    = (const int*)d_in[2];
  const int*   timei   = (const int*)d_in[3];
  const float* conv_w  = (const float*)d_in[4];
  const float* spa     = (const float*)d_in[5];
  const float* tem     = (const float*)d_in[6];
  const float* pos     = (const float*)d_in[7];
  const float* cls     = (const float*)d_in[8];
  const float* eWqkv   = (const float*)d_in[9];
  const float* ebqkv   = (const float*)d_in[10];
  const float* eWo     = (const float*)d_in[11];
  const float* ebo     = (const float*)d_in[12];
  const float* eln1w   = (const float*)d_in[13];
  const float* eln1b   = (const float*)d_in[14];
  const float* eln2w   = (const float*)d_in[15];
  const float* eln2b   = (const float*)d_in[16];
  const float* eW1     = (const float*)d_in[17];
  const float* eb1     = (const float*)d_in[18];
  const float* eW2     = (const float*)d_in[19];
  const float* eb2     = (const float*)d_in[20];
  const float* normw   = (const float*)d_in[21];
  const float* normb   = (const float*)d_in[22];
  const float* dembW   = (const float*)d_in[23];
  const float* dembb   = (const float*)d_in[24];
  const float* mtok    = (const float*)d_in[25];
  const float* dpos    = (const float*)d_in[26];
  const float* dWqkv   = (const float*)d_in[27];
  const float* dbqkv   = (const float*)d_in[28];
  const float* dWo     = (const float*)d_in[29];
  const float* dbo     = (const float*)d_in[30];
  const float* dln1w   = (const float*)d_in[31];
  const float* dln1b   = (const float*)d_in[32];
  const float* dln2w   = (const float*)d_in[33];
  const float* dln2b   = (const float*)d_in[34];
  const float* dW1     = (const float*)d_in[35];
  const float* db1     = (const float*)d_in[36];
  const float* dW2     = (const float*)d_in[37];
  const float* db2     = (const float*)d_in[38];
  const float* dnormw  = (const float*)d_in[39];
  const float* dnormb  = (const float*)d_in[40];
  const float* dpredW  = (const float*)d_in[41];
  const float* dpredb  = (const float*)d_in[42];

  // ---- workspace layout (bytes, 256-aligned). Peak ~338 MB. ----
  char* base = (char*)d_ws;
  size_t off = 0;
  auto alloc = [&](size_t bytes) -> char* {
    char* p = base + off;
    off += (bytes + 255) & ~(size_t)255;
    return p;
  };
  float* target      = (float*)alloc((size_t)B_ * L_ * TW_ * 4);   // = x0, lives to the end
  float* mflag       = (float*)alloc(L_ * 4);
  int*   ids_restore = (int*)alloc(L_ * 4);
  int*   ids_keep    = (int*)alloc(L_ * 4);
  float* lossAcc     = (float*)alloc(256);
  unsigned char* blocked = (unsigned char*)alloc((size_t)S_ * S_);
  float* xe          = (float*)alloc((size_t)B_ * SE_ * D_ * 4);
  float* big         = (float*)(base + off);
  // encoder overlay (floats from big):
  float* x     = big;                       // 14,745,600 f
  float* P     = big + 14745600;            //  2,880,000 f
  float* Bconv = big + 17625600;            //    115,200 f
  float* h     = big + 17740800;            //  3,244,032 f
  float* qkv   = big + 20984832;            //  9,732,096 f
  float* attn  = big + 30716928;            //  3,244,032 f
  float* mlp   = big + 33960960;            // 12,976,128 f
  // decoder overlay (reuses same region; encoder scratch dead by then):
  float* xd    = big;                       // 10,027,008 f
  float* hd    = big + 10027008;            // 10,027,008 f
  float* qkvd  = big + 20054016;            // 30,081,024 f
  float* attnd = big + 50135040;            // 10,027,008 f (also holds xdE: 8,650,752 f)
  float* xdE   = attnd;
  float* mlpd  = big + 60162048;            // 20,054,016 f (6528-row chunk)

  auto gemm = [&](const float* A, const float* Bm, float* Cc, const float* bias,
                  const float* res, int M, int N, int K, int gelu){
    dim3 g(N / 64, M / 64);
    gemm_f32<<<g, 256, 0, stream>>>(A, Bm, Cc, bias, res, M, N, K, gelu);
  };
  auto ln = [&](const float* xin, const float* w, const float* bb, float* outp, int rows, int dim){
    k_ln<<<rows, 256, 0, stream>>>(xin, w, bb, outp, dim);
  };

  k_zero<<<1, 64, 0, stream>>>(lossAcc);
  k_signal_norm<<<B_ * L_, 64, 0, stream>>>(signals, target);
  k_argsort<<<1, 640, 0, stream>>>(noise, mflag, ids_restore, ids_keep);
  k_build_mask<<<(S_ * S_ + 255) / 256, 256, 0, stream>>>(mflag, blocked);

  // conv patch-embed as GEMM (M=19200, N=768, K=150)
  k_prep_convw<<<(150 * D_ + 255) / 256, 256, 0, stream>>>(conv_w, Bconv);
  k_patch<<<(B_ * L_ * 150 + 255) / 256, 256, 0, stream>>>(target, P);
  gemm(P, Bconv, x, nullptr, nullptr, B_ * L_, D_, 150, 0);
  k_embed_add<<<(B_ * L_ * D_) / 256, 256, 0, stream>>>(x, chan, timei, spa, tem, pos);
  k_gather_xe<<<(B_ * SE_ * D_) / 256, 256, 0, stream>>>(x, cls, pos, ids_keep, xe);

  // ---- encoder: 12 blocks, S=132, D=768, H=12 ----
  const int Me = B_ * SE_;   // 4224
  for (int l = 0; l < DEP_; ++l){
    ln(xe, eln1w + l * D_, eln1b + l * D_, h, Me, D_);
    gemm(h, eWqkv + (size_t)l * D_ * 3 * D_, qkv, ebqkv + (size_t)l * 3 * D_, nullptr, Me, 3 * D_, D_, 0);
    k_attn_enc<<<B_ * HE_ * (SE_ / 4), 256, 0, stream>>>(qkv, attn);
    gemm(attn, eWo + (size_t)l * D_ * D_, xe, ebo + (size_t)l * D_, xe, Me, D_, D_, 0);
    ln(xe, eln2w + l * D_, eln2b + l * D_, h, Me, D_);
    gemm(h, eW1 + (size_t)l * D_ * MLP_, mlp, eb1 + (size_t)l * MLP_, nullptr, Me, MLP_, D_, 1);
    gemm(mlp, eW2 + (size_t)l * MLP_ * D_, xe, eb2 + (size_t)l * D_, xe, Me, D_, MLP_, 0);
  }
  ln(xe, normw, normb, h, Me, D_);
  gemm(h, dembW, xdE, dembb, nullptr, Me, DD_, D_, 0);   // 768 -> 512
  k_scatter_dec<<<(B_ * S_ * DD_) / 256, 256, 0, stream>>>(xdE, ids_restore, mtok, dpos, xd);

  // ---- decoder: 4 blocks, S=612, DD=512, H=16, masked attention ----
  const int Md = B_ * S_;    // 19584
  for (int l = 0; l < DDEP_; ++l){
    ln(xd, dln1w + l * DD_, dln1b + l * DD_, hd, Md, DD_);
    gemm(hd, dWqkv + (size_t)l * DD_ * 3 * DD_, qkvd, dbqkv + (size_t)l * 3 * DD_, nullptr, Md, 3 * DD_, DD_, 0);
    k_attn_dec<<<B_ * HDN_ * (S_ / 4), 256, 0, stream>>>(qkvd, blocked, attnd);
    gemm(attnd, dWo + (size_t)l * DD_ * DD_, xd, dbo + (size_t)l * DD_, xd, Md, DD_, DD_, 0);
    ln(xd, dln2w + l * DD_, dln2b + l * DD_, hd, Md, DD_);
    for (int c = 0; c < 3; ++c){              // chunk rows to cap scratch (3 x 6528)
      size_t r0 = (size_t)c * 6528;
      gemm(hd + r0 * DD_, dW1 + (size_t)l * DD_ * MLP_, mlpd, db1 + (size_t)l * MLP_, nullptr, 6528, MLP_, DD_, 1);
      gemm(mlpd, dW2 + (size_t)l * MLP_ * DD_, xd + r0 * DD_, db2 + (size_t)l * DD_, xd + r0 * DD_, 6528, DD_, MLP_, 0);
    }
  }
  ln(xd, dnormw, dnormb, hd, Md, DD_);

  k_pred_loss<<<B_ * L_, 64, 0, stream>>>(hd, dpredW, dpredb, target, mflag, lossAcc);
  k_finalize<<<1, 64, 0, stream>>>(lossAcc, (float*)d_out);
}

// Round 2
// 8892.783 us; speedup vs baseline: 4.8155x; 4.8155x over previous
//
#include <hip/hip_runtime.h>
#include <math.h>

// ---- problem constants ----
#define B_   32
#define L_   600
#define TW_  50
#define D_   768
#define MLP_ 3072
#define DEP_ 12
#define DD_  512
#define DDEP_ 4
#define C_   12
#define S_   612      // L + C
#define LK_  120      // len_keep
#define SE_  132      // encoder seq = C + len_keep
#define HE_  12       // encoder heads (hd=64)
#define HDN_ 16       // decoder heads (hd=32)
#define NPL_ 50       // L / C

typedef unsigned int  u32;
typedef unsigned short u16;
typedef __attribute__((ext_vector_type(8))) short short8;
typedef __attribute__((ext_vector_type(4))) float float4v;

__device__ __forceinline__ float wave_sum(float v){
  #pragma unroll
  for (int o = 32; o > 0; o >>= 1) v += __shfl_xor(v, o, 64);
  return v;
}
__device__ __forceinline__ float wave_max(float v){
  #pragma unroll
  for (int o = 32; o > 0; o >>= 1) v = fmaxf(v, __shfl_xor(v, o, 64));
  return v;
}
__device__ __forceinline__ float b2f(u16 u){ return __uint_as_float(((u32)u) << 16); }
__device__ __forceinline__ float blo(u32 u){ return __uint_as_float(u << 16); }
__device__ __forceinline__ float bhi(u32 u){ return __uint_as_float(u & 0xffff0000u); }
__device__ __forceinline__ u16 f2b(float f){
  u32 u = __float_as_uint(f);
  return (u16)((u + 0x7fffu + ((u >> 16) & 1u)) >> 16);   // RNE
}

// per-token signal normalization: target = (sig - mu)/sqrt(var_ddof1 + 1e-6)
__global__ void k_signal_norm(const float* __restrict__ sig, float* __restrict__ tgt){
  int row = blockIdx.x; int lane = threadIdx.x;
  const float* p = sig + (size_t)row * TW_;
  float v = (lane < TW_) ? p[lane] : 0.f;
  float mean = wave_sum(v) * (1.f / TW_);
  float d = (lane < TW_) ? (v - mean) : 0.f;
  float var = wave_sum(d * d) * (1.f / (TW_ - 1));
  float rstd = rsqrtf(var + 1e-6f);
  if (lane < TW_) tgt[(size_t)row * TW_ + lane] = d * rstd;
}

// rank-based argsort of noise[0] (L=600, O(L^2), one block)
__global__ void k_argsort(const float* __restrict__ noise, float* __restrict__ m,
                          int* __restrict__ ids_restore, int* __restrict__ ids_keep){
  __shared__ float ns[L_];
  int t = threadIdx.x;
  if (t < L_) ns[t] = noise[t];
  __syncthreads();
  if (t < L_){
    float v = ns[t]; int r = 0;
    for (int j = 0; j < L_; ++j){
      float u = ns[j];
      r += (u < v) || (u == v && j < t);   // stable ascending
    }
    ids_restore[t] = r;
    m[t] = (r >= LK_) ? 1.f : 0.f;
    if (r < LK_) ids_keep[r] = t;
  }
}

// conv_w (D,TW,3) -> Bconv bf16 [768][160] (K padded 150->160, kk = k*TW+i)
__global__ void k_prep_convw(const float* __restrict__ w, u16* __restrict__ Bc){
  int idx = blockIdx.x * 256 + threadIdx.x;   // 768*160
  int n = idx / 160; int kk = idx % 160;
  u16 v = 0;
  if (kk < 150){
    int i = kk % TW_; int k = kk / TW_;
    v = f2b(w[(size_t)n * 150 + i * 3 + k]);
  }
  Bc[idx] = v;
}

// im2col bf16 with wrap padding, K padded to 160
__global__ void k_patch(const float* __restrict__ x0, u16* __restrict__ P){
  int idx = blockIdx.x * 256 + threadIdx.x;   // B*L*160
  int kk = idx % 160; int mrow = idx / 160;
  if (kk >= 150){ P[idx] = 0; return; }
  int b = mrow / L_, l = mrow % L_;
  int i = kk % TW_, k = kk / TW_;
  int lw = l + k - 1; if (lw < 0) lw += L_; if (lw >= L_) lw -= L_;
  P[idx] = f2b(x0[((size_t)b * L_ + lw) * TW_ + i]);
}

// x += spa_table[chan] + tem_table[time] + pos_embed[C+l]   (x fp32)
__global__ void k_embed_add(float* __restrict__ x, const int* __restrict__ chan,
                            const int* __restrict__ timei, const float* __restrict__ spa,
                            const float* __restrict__ tem, const float* __restrict__ pos){
  int idx = blockIdx.x * 256 + threadIdx.x;
  int d = idx % D_; int rl = idx / D_;
  int l = rl % L_;
  x[idx] += spa[(size_t)chan[rl] * D_ + d] + tem[(size_t)timei[rl] * D_ + d]
          + pos[(size_t)(C_ + l) * D_ + d];
}

// xe(fp32) = [cls_token + pos_embed[:C] ; x[:, ids_keep, :]]
__global__ void k_gather_xe(const float* __restrict__ x, const float* __restrict__ cls,
                            const float* __restrict__ pos, const int* __restrict__ ids_keep,
                            float* __restrict__ xe){
  int idx = blockIdx.x * 256 + threadIdx.x;
  int d = idx % D_; int rs = idx / D_;
  int b = rs / SE_, s = rs % SE_;
  float v;
  if (s < C_) v = cls[(size_t)s * D_ + d] + pos[(size_t)s * D_ + d];
  else        v = x[((size_t)b * L_ + ids_keep[s - C_]) * D_ + d];
  xe[idx] = v;
}

// weight transpose+cvt: src [cnt][K][N] f32 -> dst [cnt][N][K] bf16 (K,N % 32 == 0)
__global__ void k_wt(const float* __restrict__ src, u16* __restrict__ dst, int K, int N){
  int l = blockIdx.z;
  src += (size_t)l * K * N; dst += (size_t)l * N * K;
  __shared__ float t[32][33];
  int k0 = blockIdx.y * 32, n0 = blockIdx.x * 32;
  int tx = threadIdx.x, ty = threadIdx.y;  // 32 x 8
  #pragma unroll
  for (int r = 0; r < 4; ++r)
    t[ty + 8 * r][tx] = src[(size_t)(k0 + ty + 8 * r) * N + n0 + tx];
  __syncthreads();
  #pragma unroll
  for (int r = 0; r < 4; ++r)
    dst[(size_t)(n0 + ty + 8 * r) * K + k0 + tx] = f2b(t[tx][ty + 8 * r]);
}

// wave-per-row LayerNorm; outF xor outB
template<int DIM>
__launch_bounds__(256)
__global__ void k_ln(const float* __restrict__ xin, const float* __restrict__ w,
                     const float* __restrict__ bb, float* __restrict__ outF,
                     u16* __restrict__ outB){
  int row = blockIdx.x * 4 + (threadIdx.x >> 6);
  int lane = threadIdx.x & 63;
  const float4* p = (const float4*)(xin + (size_t)row * DIM);
  const int CNT = DIM >> 8;    // 768->3, 512->2
  float4 vals[CNT];
  float s = 0.f, sq = 0.f;
  #pragma unroll
  for (int i = 0; i < CNT; ++i){
    float4 v = p[lane + 64 * i]; vals[i] = v;
    s  += v.x + v.y + v.z + v.w;
    sq += v.x * v.x + v.y * v.y + v.z * v.z + v.w * v.w;
  }
  s = wave_sum(s); sq = wave_sum(sq);
  float mean = s / DIM;
  float rstd = rsqrtf(sq / DIM - mean * mean + 1e-5f);
  const float4* wv4 = (const float4*)w;
  const float4* bv4 = (const float4*)bb;
  #pragma unroll
  for (int i = 0; i < CNT; ++i){
    float4 v = vals[i]; float4 wv = wv4[lane + 64 * i]; float4 bv = bv4[lane + 64 * i];
    float o0 = (v.x - mean) * rstd * wv.x + bv.x;
    float o1 = (v.y - mean) * rstd * wv.y + bv.y;
    float o2 = (v.z - mean) * rstd * wv.z + bv.z;
    float o3 = (v.w - mean) * rstd * wv.w + bv.w;
    size_t idx = (size_t)row * DIM + (lane + 64 * i) * 4;
    if (outF){
      float4 o = {o0, o1, o2, o3};
      *(float4*)(outF + idx) = o;
    } else {
      uint2 pk;
      pk.x = (u32)f2b(o0) | ((u32)f2b(o1) << 16);
      pk.y = (u32)f2b(o2) | ((u32)f2b(o3) << 16);
      *(uint2*)(outB + idx) = pk;
    }
  }
}

// bf16 MFMA GEMM: out[M,N] = A[M,K](bf16) @ Bt[N,K]^T(bf16) (+bias)(gelu)(+res)
// M%128==0, N%128==0, K%32==0; A,Bt 16B-aligned, K*2 % 16 == 0.
__launch_bounds__(256, 2)
__global__ void gemm_bf16(const u16* __restrict__ A, const u16* __restrict__ Bt,
                          const float* __restrict__ bias, const float* __restrict__ res,
                          float* __restrict__ outF, u16* __restrict__ outB,
                          int M, int N, int K, int gelu){
  __shared__ u16 As[128 * 32];
  __shared__ u16 Bs[128 * 32];
  int tid = threadIdx.x, wave = tid >> 6, lane = tid & 63;
  int bm = blockIdx.y * 128, bn = blockIdx.x * 128;
  int wm = (wave >> 1) * 64, wn = (wave & 1) * 64;
  int t0 = wave * 2, t1 = t0 + 1;
  int sr0 = t0 * 16 + (lane >> 2), sr1 = t1 * 16 + (lane >> 2);
  int sc = (lane & 3) * 8;
  const u16* ga0 = A  + (size_t)(bm + sr0) * K + sc;
  const u16* ga1 = A  + (size_t)(bm + sr1) * K + sc;
  const u16* gb0 = Bt + (size_t)(bn + sr0) * K + sc;
  const u16* gb1 = Bt + (size_t)(bn + sr1) * K + sc;
  int fa = (wm + (lane & 15)) * 32 + (lane >> 4) * 8;
  int fb = (wn + (lane & 15)) * 32 + (lane >> 4) * 8;
  float4v acc[4][4] = {};
  for (int k0 = 0; k0 < K; k0 += 32){
    __syncthreads();
    __builtin_amdgcn_global_load_lds((const __attribute__((address_space(1))) void*)(ga0 + k0),
        (__attribute__((address_space(3))) void*)&As[t0 * 512], 16, 0, 0);
    __builtin_amdgcn_global_load_lds((const __attribute__((address_space(1))) void*)(ga1 + k0),
        (__attribute__((address_space(3))) void*)&As[t1 * 512], 16, 0, 0);
    __builtin_amdgcn_global_load_lds((const __attribute__((address_space(1))) void*)(gb0 + k0),
        (__attribute__((address_space(3))) void*)&Bs[t0 * 512], 16, 0, 0);
    __builtin_amdgcn_global_load_lds((const __attribute__((address_space(1))) void*)(gb1 + k0),
        (__attribute__((address_space(3))) void*)&Bs[t1 * 512], 16, 0, 0);
    __syncthreads();
    short8 af[4], bf[4];
    #pragma unroll
    for (int i = 0; i < 4; ++i) af[i] = *(const short8*)&As[fa + i * 16 * 32];
    #pragma unroll
    for (int i = 0; i < 4; ++i) bf[i] = *(const short8*)&Bs[fb + i * 16 * 32];
    #pragma unroll
    for (int mt = 0; mt < 4; ++mt)
      #pragma unroll
      for (int nt = 0; nt < 4; ++nt)
        acc[mt][nt] = __builtin_amdgcn_mfma_f32_16x16x32_bf16(af[mt], bf[nt], acc[mt][nt], 0, 0, 0);
  }
  #pragma unroll
  for (int nt = 0; nt < 4; ++nt){
    int col = bn + wn + nt * 16 + (lane & 15);
    float bv = bias ? bias[col] : 0.f;
    #pragma unroll
    for (int mt = 0; mt < 4; ++mt){
      #pragma unroll
      for (int r = 0; r < 4; ++r){
        int row = bm + wm + mt * 16 + (lane >> 4) * 4 + r;
        float v = acc[mt][nt][r] + bv;
        if (gelu){
          float u = 0.7978845608028654f * (v + 0.044715f * v * v * v);
          v = 0.5f * v * (2.f - 2.f / (__expf(2.f * u) + 1.f));   // 0.5v(1+tanh(u))
        }
        if (res) v += res[(size_t)row * N + col];
        if (outF) outF[(size_t)row * N + col] = v;
        else      outB[(size_t)row * N + col] = f2b(v);
      }
    }
  }
}

// encoder attention, LDS-staged K/V (bf16 qkv). 2 blocks per (b,h), 66 q each.
__launch_bounds__(256)
__global__ void k_attn_enc(const u16* __restrict__ qkv, u16* __restrict__ out){
  int part = blockIdx.x & 1;
  int bh = blockIdx.x >> 1;
  int h = bh % HE_, b = bh / HE_;
  __shared__ u32 Ks[SE_ * 33];   // rows padded to 33 words -> conflict-free
  __shared__ u32 Vs[SE_ * 33];
  __shared__ float ps[4][SE_];
  int tid = threadIdx.x, wave = tid >> 6, lane = tid & 63;
  const u32* kb = (const u32*)(qkv + (size_t)(b * SE_) * 2304 + 768 + h * 64);
  const u32* vb = kb + 384;   // +768 ushorts
  for (int i = tid; i < SE_ * 32; i += 256){
    int row = i >> 5, j = i & 31;
    Ks[row * 33 + j] = kb[(size_t)row * 1152 + j];
    Vs[row * 33 + j] = vb[(size_t)row * 1152 + j];
  }
  __syncthreads();
  for (int q = part * 66 + wave; q < part * 66 + 66; q += 4){
    const u32* qr = (const u32*)(qkv + (size_t)(b * SE_ + q) * 2304 + h * 64);
    u32 qreg[32];
    #pragma unroll
    for (int j = 0; j < 32; ++j) qreg[j] = qr[j];
    float sc[3]; float mx = -1e30f;
    #pragma unroll
    for (int t = 0; t < 3; ++t){
      int k = lane + t * 64;
      if (k < SE_){
        const u32* kr = &Ks[k * 33];
        float dot = 0.f;
        #pragma unroll
        for (int j = 0; j < 32; ++j){
          u32 ku = kr[j], qu = qreg[j];
          dot += blo(qu) * blo(ku) + bhi(qu) * bhi(ku);
        }
        sc[t] = dot * 0.125f;
        mx = fmaxf(mx, sc[t]);
      } else sc[t] = -1e30f;
    }
    mx = wave_max(mx);
    float sum = 0.f;
    #pragma unroll
    for (int t = 0; t < 3; ++t){
      int k = lane + t * 64;
      if (k < SE_){ float e = __expf(sc[t] - mx); ps[wave][k] = e; sum += e; }
    }
    sum = wave_sum(sum);
    float inv = 1.f / sum;
    int dw = lane >> 1, hi = lane & 1;
    float o = 0.f;
    for (int k = 0; k < SE_; ++k){
      u32 u = Vs[k * 33 + dw];
      o += ps[wave][k] * (hi ? bhi(u) : blo(u));
    }
    out[(size_t)(b * SE_ + q) * D_ + h * 64 + lane] = f2b(o * inv);
  }
}

// decoder attention, mask-structured: cls q -> 51 keys, masked q -> 13, unmasked -> 121
__launch_bounds__(256)
__global__ void k_attn_dec(const u16* __restrict__ qkv, const float* __restrict__ m,
                           const int* __restrict__ keep, u16* __restrict__ out){
  int bid = blockIdx.x;
  int qt = bid % (S_ / 4); int bh = bid / (S_ / 4);
  int h = bh % HDN_; int b = bh / HDN_;
  int tid = threadIdx.x, wave = tid >> 6, lane = tid & 63;
  int q = qt * 4 + wave;
  __shared__ float qs[4][32];
  __shared__ float ps[4][128];
  __shared__ int   ks[4][128];
  __shared__ int   keep_s[LK_];
  if (tid < LK_) keep_s[tid] = keep[tid];
  const u16* qr = qkv + (size_t)(b * S_ + q) * 1536 + h * 32;
  if (lane < 32) qs[wave][lane] = b2f(qr[lane]);
  __syncthreads();
  bool isCls = (q < C_);
  int ii = q - C_;
  int lead = 0, off = 0; bool msk = false;
  if (!isCls){ lead = ii / NPL_; off = ii % NPL_; msk = (m[ii] > 0.f); }
  int nk = isCls ? (NPL_ + 1) : (msk ? (C_ + 1) : (LK_ + 1));
  float sc0 = -1e30f, sc1 = -1e30f;
  float mx = -1e30f;
  #pragma unroll
  for (int r = 0; r < 2; ++r){
    int t = lane + r * 64;
    if (t < nk){
      int key;
      if (t == 0)      key = isCls ? q : lead;
      else if (isCls)  key = C_ + q * NPL_ + (t - 1);
      else if (msk)    key = C_ + (t - 1) * NPL_ + off;
      else             key = C_ + keep_s[t - 1];
      ks[wave][t] = key;
      const u32* kr = (const u32*)(qkv + (size_t)(b * S_ + key) * 1536 + 512 + h * 32);
      float dot = 0.f;
      #pragma unroll
      for (int j = 0; j < 16; ++j){
        u32 u = kr[j];
        dot += qs[wave][2 * j] * blo(u) + qs[wave][2 * j + 1] * bhi(u);
      }
      float s = dot * 0.17677669529663687f;   // 1/sqrt(32)
      if (r == 0) sc0 = s; else sc1 = s;
      mx = fmaxf(mx, s);
    }
  }
  mx = wave_max(mx);
  float sum = 0.f;
  if (lane < nk)      { float e = __expf(sc0 - mx); ps[wave][lane]      = e; sum += e; }
  if (lane + 64 < nk) { float e = __expf(sc1 - mx); ps[wave][lane + 64] = e; sum += e; }
  sum = wave_sum(sum);
  float inv = 1.f / sum;
  int d = lane & 31, half = lane >> 5;
  const u16* vb = qkv + (size_t)(b * S_) * 1536 + 1024 + h * 32 + d;
  float o = 0.f;
  for (int t = half; t < nk; t += 2) o += ps[wave][t] * b2f(vb[(size_t)ks[wave][t] * 1536]);
  o += __shfl_xor(o, 32, 64);
  if (half == 0) out[(size_t)(b * S_ + q) * DD_ + h * 32 + d] = f2b(o * inv);
}

// decoder input: unshuffle + mask tokens + dec_pos_embed (fp32)
__global__ void k_scatter_dec(const float* __restrict__ xdE, const int* __restrict__ ids_restore,
                              const float* __restrict__ mask_token, const float* __restrict__ dpos,
                              float* __restrict__ xd){
  int idx = blockIdx.x * 256 + threadIdx.x;
  int d = idx % DD_; int rs = idx / DD_;
  int b = rs / S_, s = rs % S_;
  float v;
  if (s < C_) v = xdE[((size_t)(b * SE_ + s)) * DD_ + d];
  else {
    int r = ids_restore[s - C_];
    v = (r < LK_) ? xdE[((size_t)(b * SE_ + C_ + r)) * DD_ + d] : mask_token[d];
  }
  xd[idx] = v + dpos[(size_t)s * DD_ + d];
}

// fused pred GEMM row + MSE + masked atomic accumulate (hd fp32)
__global__ void k_pred_loss(const float* __restrict__ hd, const float* __restrict__ Wp,
                            const float* __restrict__ bp, const float* __restrict__ tgt,
                            const float* __restrict__ m, float* __restrict__ loss){
  int r = blockIdx.x;          // b*L + i
  int i = r % L_;
  if (m[i] == 0.f) return;
  int b = r / L_;
  __shared__ float hrow[DD_];
  const float* src = hd + ((size_t)(b * S_ + C_ + i)) * DD_;
  for (int j = threadIdx.x; j < DD_; j += 64) hrow[j] = src[j];
  __syncthreads();
  int n = threadIdx.x;
  float acc = 0.f;
  if (n < TW_){
    for (int k = 0; k < DD_; ++k) acc += hrow[k] * Wp[(size_t)k * TW_ + n];
    acc += bp[n];
    float e = acc - tgt[(size_t)r * TW_ + n];
    acc = e * e;
  }
  acc = wave_sum(acc);
  if (threadIdx.x == 0) atomicAdd(loss, acc * (1.f / TW_));
}

__global__ void k_zero(float* p){ if (threadIdx.x == 0) p[0] = 0.f; }
__global__ void k_finalize(const float* loss, float* out){
  if (threadIdx.x == 0) out[0] = loss[0] * (1.f / (float)(L_ - LK_));   // sum(m)=480
}

extern "C" void kernel_launch(void* const* d_in, const int* in_sizes, int n_in,
                              void* d_out, int out_size, void* d_ws, size_t ws_size,
                              hipStream_t stream){
  (void)in_sizes; (void)n_in; (void)out_size; (void)ws_size;
  const float* signals = (const float*)d_in[0];
  const float* noise   = (const float*)d_in[1];
  const int*   chan    = (const int*)d_in[2];
  const int*   timei   = (const int*)d_in[3];
  const float* conv_w  = (const float*)d_in[4];
  const float* spa     = (const float*)d_in[5];
  const float* tem     = (const float*)d_in[6];
  const float* pos     = (const float*)d_in[7];
  const float* cls     = (const float*)d_in[8];
  const float* eWqkv   = (const float*)d_in[9];
  const float* ebqkv   = (const float*)d_in[10];
  const float* eWo     = (const float*)d_in[11];
  const float* ebo     = (const float*)d_in[12];
  const float* eln1w   = (const float*)d_in[13];
  const float* eln1b   = (const float*)d_in[14];
  const float* eln2w   = (const float*)d_in[15];
  const float* eln2b   = (const float*)d_in[16];
  const float* eW1     = (const float*)d_in[17];
  const float* eb1     = (const float*)d_in[18];
  const float* eW2     = (const float*)d_in[19];
  const float* eb2     = (const float*)d_in[20];
  const float* normw   = (const float*)d_in[21];
  const float* normb   = (const float*)d_in[22];
  const float* dembW   = (const float*)d_in[23];
  const float* dembb   = (const float*)d_in[24];
  const float* mtok    = (const float*)d_in[25];
  const float* dpos    = (const float*)d_in[26];
  const float* dWqkv   = (const float*)d_in[27];
  const float* dbqkv   = (const float*)d_in[28];
  const float* dWo     = (const float*)d_in[29];
  const float* dbo     = (const float*)d_in[30];
  const float* dln1w   = (const float*)d_in[31];
  const float* dln1b   = (const float*)d_in[32];
  const float* dln2w   = (const float*)d_in[33];
  const float* dln2b   = (const float*)d_in[34];
  const float* dW1     = (const float*)d_in[35];
  const float* db1     = (const float*)d_in[36];
  const float* dW2     = (const float*)d_in[37];
  const float* db2     = (const float*)d_in[38];
  const float* dnormw  = (const float*)d_in[39];
  const float* dnormb  = (const float*)d_in[40];
  const float* dpredW  = (const float*)d_in[41];
  const float* dpredb  = (const float*)d_in[42];

  // ---- workspace layout (total ~255 MB) ----
  char* base = (char*)d_ws;
  size_t off = 0;
  auto alloc = [&](size_t bytes) -> char* {
    char* p = base + off;
    off += (bytes + 255) & ~(size_t)255;
    return p;
  };
  float* target      = (float*)alloc((size_t)B_ * L_ * TW_ * 4);
  float* mflag       = (float*)alloc(L_ * 4);
  int*   ids_restore = (int*)alloc(L_ * 4);
  int*   ids_keep    = (int*)alloc(L_ * 4);
  float* lossAcc     = (float*)alloc(256);
  float* xe          = (float*)alloc((size_t)B_ * SE_ * D_ * 4);
  u16*   encW        = (u16*)alloc((size_t)7077888 * 2);    // per-layer enc weights
  u16*   decW        = (u16*)alloc((size_t)17170432 * 2);   // all dec weights + demb
  char*  arena       = alloc((size_t)189136896);

  // enc per-layer weight views (ushort offsets)
  u16* eWqkvT = encW;                  // 2304x768
  u16* eWoT   = encW + 1769472;        // 768x768
  u16* eW1T   = encW + 2359296;        // 3072x768
  u16* eW2T   = encW + 4718592;        // 768x3072
  // dec weight views
  u16* dWqkvT = decW;                  // 4 x 1536x512
  u16* dWoT   = decW + 3145728;        // 4 x 512x512
  u16* dW1T   = decW + 4194304;        // 4 x 3072x512
  u16* dW2T   = decW + 10485760;       // 4 x 512x3072
  u16* dembWT = decW + 16777216;       // 512x768
  // encoder arena overlay
  float* x     = (float*)(arena);                    // 19200x768 f32
  u16*   P     = (u16*)(arena + 58982400);           // 19200x160
  u16*   Bconv = (u16*)(arena + 65126400);           // 768x160
  u16*   qkv   = (u16*)(arena + 65372160);           // 4224x2304
  u16*   attn  = (u16*)(arena + 84836352);           // 4224x768
  u16*   mlp   = (u16*)(arena + 91324416);           // 4224x3072
  u16*   h     = (u16*)(arena + 117276672);          // 4224x768
  // decoder arena overlay (h only needed until demb gemm; xdE placed below h)
  float* xdE   = (float*)(arena);                    // 4224x512 f32
  float* xd    = (float*)(arena + 8650752);          // 19584x512 f32
  u16*   hd_b  = (u16*)(arena + 48758784);           // 19584x512
  u16*   attnd = (u16*)(arena + 68812800);           // 19584x512
  u16*   qkvd  = (u16*)(arena + 88866816);           // 19584x1536 (later reused as hdF f32)
  u16*   mlpd  = (u16*)(arena + 149028864);          // 6528x3072
  float* hdF   = (float*)qkvd;

  auto gemm = [&](const u16* A, const u16* Bt, const float* bias, const float* res,
                  float* oF, u16* oB, int M, int N, int K, int gelu){
    dim3 g(N / 128, M / 128);
    gemm_bf16<<<g, 256, 0, stream>>>(A, Bt, bias, res, oF, oB, M, N, K, gelu);
  };

  k_zero<<<1, 64, 0, stream>>>(lossAcc);
  k_signal_norm<<<B_ * L_, 64, 0, stream>>>(signals, target);
  k_argsort<<<1, 640, 0, stream>>>(noise, mflag, ids_restore, ids_keep);
  k_prep_convw<<<(768 * 160) / 256, 256, 0, stream>>>(conv_w, Bconv);
  k_patch<<<(B_ * L_ * 160) / 256, 256, 0, stream>>>(target, P);

  // dec weights upfront
  k_wt<<<dim3(48, 16, 4), dim3(32, 8), 0, stream>>>(dWqkv, dWqkvT, 512, 1536);
  k_wt<<<dim3(16, 16, 4), dim3(32, 8), 0, stream>>>(dWo,   dWoT,   512, 512);
  k_wt<<<dim3(96, 16, 4), dim3(32, 8), 0, stream>>>(dW1,   dW1T,   512, 3072);
  k_wt<<<dim3(16, 96, 4), dim3(32, 8), 0, stream>>>(dW2,   dW2T,   3072, 512);
  k_wt<<<dim3(16, 24, 1), dim3(32, 8), 0, stream>>>(dembW, dembWT, 768, 512);

  // conv patch-embed as GEMM (M=19200, N=768, K=160)
  gemm(P, Bconv, nullptr, nullptr, x, nullptr, B_ * L_, D_, 160, 0);
  k_embed_add<<<(B_ * L_ * D_) / 256, 256, 0, stream>>>(x, chan, timei, spa, tem, pos);
  k_gather_xe<<<(B_ * SE_ * D_) / 256, 256, 0, stream>>>(x, cls, pos, ids_keep, xe);

  // ---- encoder ----
  const int Me = B_ * SE_;   // 4224
  for (int l = 0; l < DEP_; ++l){
    k_wt<<<dim3(72, 24, 1), dim3(32, 8), 0, stream>>>(eWqkv + (size_t)l * D_ * 3 * D_, eWqkvT, 768, 2304);
    k_wt<<<dim3(24, 24, 1), dim3(32, 8), 0, stream>>>(eWo   + (size_t)l * D_ * D_,     eWoT,   768, 768);
    k_wt<<<dim3(96, 24, 1), dim3(32, 8), 0, stream>>>(eW1   + (size_t)l * D_ * MLP_,   eW1T,   768, 3072);
    k_wt<<<dim3(24, 96, 1), dim3(32, 8), 0, stream>>>(eW2   + (size_t)l * MLP_ * D_,   eW2T,   3072, 768);
    k_ln<768><<<Me / 4, 256, 0, stream>>>(xe, eln1w + l * D_, eln1b + l * D_, nullptr, h);
    gemm(h, eWqkvT, ebqkv + (size_t)l * 3 * D_, nullptr, nullptr, qkv, Me, 3 * D_, D_, 0);
    k_attn_enc<<<B_ * HE_ * 2, 256, 0, stream>>>(qkv, attn);
    gemm(attn, eWoT, ebo + (size_t)l * D_, xe, xe, nullptr, Me, D_, D_, 0);
    k_ln<768><<<Me / 4, 256, 0, stream>>>(xe, eln2w + l * D_, eln2b + l * D_, nullptr, h);
    gemm(h, eW1T, eb1 + (size_t)l * MLP_, nullptr, nullptr, mlp, Me, MLP_, D_, 1);
    gemm(mlp, eW2T, eb2 + (size_t)l * D_, xe, xe, nullptr, Me, D_, MLP_, 0);
  }
  k_ln<768><<<Me / 4, 256, 0, stream>>>(xe, normw, normb, nullptr, h);
  gemm(h, dembWT, dembb, nullptr, xdE, nullptr, Me, DD_, D_, 0);
  k_scatter_dec<<<(B_ * S_ * DD_) / 256, 256, 0, stream>>>(xdE, ids_restore, mtok, dpos, xd);

  // ---- decoder ----
  const int Md = B_ * S_;    // 19584
  for (int l = 0; l < DDEP_; ++l){
    k_ln<512><<<Md / 4, 256, 0, stream>>>(xd, dln1w + l * DD_, dln1b + l * DD_, nullptr, hd_b);
    gemm(hd_b, dWqkvT + (size_t)l * 1536 * 512, dbqkv + (size_t)l * 3 * DD_, nullptr,
         nullptr, qkvd, Md, 3 * DD_, DD_, 0);
    k_attn_dec<<<B_ * HDN_ * (S_ / 4), 256, 0, stream>>>(qkvd, mflag, ids_keep, attnd);
    gemm(attnd, dWoT + (size_t)l * 512 * 512, dbo + (size_t)l * DD_, xd, xd, nullptr, Md, DD_, DD_, 0);
    k_ln<512><<<Md / 4, 256, 0, stream>>>(xd, dln2w + l * DD_, dln2b + l * DD_, nullptr, hd_b);
    for (int c = 0; c < 3; ++c){
      size_t r0 = (size_t)c * 6528;
      gemm(hd_b + r0 * DD_, dW1T + (size_t)l * 3072 * 512, db1 + (size_t)l * MLP_, nullptr,
           nullptr, mlpd, 6528, MLP_, DD_, 1);
      gemm(mlpd, dW2T + (size_t)l * 512 * 3072, db2 + (size_t)l * DD_, xd + r0 * DD_,
           xd + r0 * DD_, nullptr, 6528, DD_, MLP_, 0);
    }
  }
  k_ln<512><<<Md / 4, 256, 0, stream>>>(xd, dnormw, dnormb, hdF, nullptr);

  k_pred_loss<<<B_ * L_, 64, 0, stream>>>(hdF, dpredW, dpredb, target, mflag, lossAcc);
  k_finalize<<<1, 64, 0, stream>>>(lossAcc, (float*)d_out);
}